// Round 3
// baseline (7898.566 us; speedup 1.0000x reference)
//
#include <hip/hip_runtime.h>
#include <cstdint>
#include <cstddef>

typedef _Float16 half_t;
typedef _Float16 half2_t __attribute__((ext_vector_type(2)));
typedef _Float16 half8_t __attribute__((ext_vector_type(8)));
typedef float   float4_t __attribute__((ext_vector_type(4)));

#define L_N 2
#define B_N 32
#define S_N 2048
#define H_N 256
#define G_N 1024            // 4H
#define M_N (B_N*S_N)       // 65536

// Recurrent kernel: 512 threads = 2 K-halves x 256 cells.
// Per thread: 4 gate rows x 64 pairs; KREG2 pairs in VGPRs, KLDS2 in LDS.
#define KREG2 48
#define KLDS2 16
#define SMEM_WT   (KLDS2*512*16)            // 131072 B weight tiles
#define SMEM_HB   (2*128*4)                 // double-buffered h pairs
#define SMEM_RED  (256*16)                  // float4 partial-sum reduce
#define SMEM_BYTES (SMEM_WT + SMEM_HB + SMEM_RED)

// ws layout (bytes)
#define WS_A0   0ull                 // fp16 [M][H]: layer-0 A; later reused as h0 sequence
#define WS_XP   33554432ull          // fp16 [M][G]: input projection, packed [m][cell][4]
#define WS_WI   167772160ull         // fp16 [L][G][H]
#define WS_WH   168820736ull         // fp16 [L][G][H]
#define WS_BSUM 169869312ull         // f32 [L][G]  (b_ih + b_hh)

__global__ void cvt_f32_f16(const float* __restrict__ in, half_t* __restrict__ out, int n){
  int i = blockIdx.x*256 + threadIdx.x;
  if (i < n) out[i] = (half_t)in[i];
}

__global__ void make_bsum(const float* __restrict__ bi, const float* __restrict__ bh,
                          float* __restrict__ bs, int n){
  int i = blockIdx.x*256 + threadIdx.x;
  if (i < n) bs[i] = bi[i] + bh[i];
}

// XP[m, cell, gate] = sum_k A[m,k] * W[gate*256+cell, k] + bsum[...]
// A:[M][256] fp16, W:[1024][256] fp16. Output packed so one cell's 4 gate
// pre-activations are adjacent: XP[m*1024 + cell*4 + gate].
__global__ __launch_bounds__(256) void gemm_xp(
    const half_t* __restrict__ A, const half_t* __restrict__ W,
    const float* __restrict__ bsum, half_t* __restrict__ XP)
{
  const int wave = threadIdx.x >> 6;
  const int lane = threadIdx.x & 63;
  const int l15 = lane & 15, quad = lane >> 4;
  const int m0 = blockIdx.x*64 + wave*16;
  const int n0 = blockIdx.y*64;
  float4_t acc[4] = {{0,0,0,0},{0,0,0,0},{0,0,0,0},{0,0,0,0}};
  const half_t* arow = A + (size_t)(m0 + l15)*H_N + quad*8;
  const half_t* brow[4];
  #pragma unroll
  for (int nt=0; nt<4; ++nt)
    brow[nt] = W + (size_t)(n0 + nt*16 + l15)*H_N + quad*8;
  #pragma unroll
  for (int k0=0; k0<H_N; k0+=32){
    half8_t af = *(const half8_t*)(arow + k0);
    #pragma unroll
    for (int nt=0; nt<4; ++nt){
      half8_t bf = *(const half8_t*)(brow[nt] + k0);
      acc[nt] = __builtin_amdgcn_mfma_f32_16x16x32_f16(af, bf, acc[nt], 0, 0, 0);
    }
  }
  #pragma unroll
  for (int nt=0; nt<4; ++nt){
    const int col = n0 + nt*16 + l15;          // gate row g in [0,1024)
    const int cell = col & 255, gate = col >> 8;
    const float bs = bsum[col];
    #pragma unroll
    for (int r=0; r<4; ++r){
      XP[(size_t)(m0 + quad*4 + r)*G_N + cell*4 + gate] = (half_t)(acc[nt][r] + bs);
    }
  }
}

__device__ __forceinline__ float sigf(float x){ return 1.f/(1.f + __expf(-x)); }
__device__ __forceinline__ float tanh_f(float x){ return 1.f - 2.f/(__expf(2.f*x) + 1.f); }

// Persistent per-batch-chain LSTM recurrence. 1 block = 1 chain = 1 CU.
// 512 threads: tid = (kh<<8)|j. Thread owns gates {j,j+256,j+512,j+768} over
// K-pairs [kh*64, kh*64+64). h broadcast: one ds_read_b32 per wave puts the
// half's 64 h-pairs into 64 lanes; v_readlane -> SGPR feeds fdot2 directly
// (VOP3P scalar operand), eliminating all per-thread LDS h reads.
__global__ __launch_bounds__(512,2) void lstm_rec(
    const uint32_t* __restrict__ Wp,   // fp16-pair view of Wh [1024][128]
    const half_t*  __restrict__ xp,    // [M][1024], packed [m][cell][4], biases folded
    half_t* __restrict__ h16,          // layer-0 h sequence out (fp16)
    float*  __restrict__ h32,          // layer-1 h sequence out (fp32, = d_out x)
    float*  __restrict__ hT, float* __restrict__ cT, int wr32)
{
  extern __shared__ unsigned char smem[];
  uint4*    wlds = (uint4*)smem;                     // [KLDS2][512]
  uint32_t* hbuf = (uint32_t*)(smem + SMEM_WT);      // [2][128] h pairs
  float4*   red  = (float4*)(smem + SMEM_WT + SMEM_HB); // [256]
  const int tid = threadIdx.x;
  const int j    = tid & 255;
  const int kh   = tid >> 8;
  const int lane = tid & 63;
  const int b  = blockIdx.x;

  // --- VGPR-resident weights: pairs kh*64 + [0, KREG2) of each of 4 gate rows
  uint32_t wreg[4][KREG2];
  #pragma unroll
  for (int q=0; q<4; ++q){
    const uint32_t* wp = Wp + (size_t)(q*256 + j)*128 + kh*64;
    #pragma unroll
    for (int k=0; k<KREG2; ++k) wreg[q][k] = wp[k];
  }
  // --- LDS-resident weights: pairs kh*64 + KREG2 + [0, KLDS2), 4 gates packed per uint4
  {
    const uint32_t* w0 = Wp + (size_t)(  0 + j)*128 + kh*64 + KREG2;
    const uint32_t* w1 = Wp + (size_t)(256 + j)*128 + kh*64 + KREG2;
    const uint32_t* w2 = Wp + (size_t)(512 + j)*128 + kh*64 + KREG2;
    const uint32_t* w3 = Wp + (size_t)(768 + j)*128 + kh*64 + KREG2;
    #pragma unroll
    for (int k=0; k<KLDS2; ++k){
      uint4 v; v.x = w0[k]; v.y = w1[k]; v.z = w2[k]; v.w = w3[k];
      wlds[k*512 + tid] = v;
    }
  }
  if (tid < 128) hbuf[128 + tid] = 0u;   // initial h (read buffer of t=0) = 0
  float c = 0.f;
  __syncthreads();

  const size_t base = (size_t)b * S_N;
  // software-pipelined xp load (kh=0 threads only; wave-uniform branch)
  uint2 xv = {0,0};
  if (!kh) xv = *(const uint2*)(xp + base*G_N + j*4);

  for (int t=0; t<S_N; ++t){
    // one b32 per wave: lane l holds h-pair (kh*64 + l) of previous step
    const uint32_t hv = hbuf[((t+1)&1)*128 + kh*64 + lane];

    // prefetch next step's xp early so it overlaps the dot chain
    uint2 xnext = {0,0};
    if (!kh && t+1 < S_N) xnext = *(const uint2*)(xp + (base+t+1)*G_N + j*4);

    float a0=0.f, a1=0.f, a2=0.f, a3=0.f;

    // VGPR-weight section: h2 via readlane (SGPR operand to fdot2)
    #pragma unroll
    for (int k=0; k<KREG2; ++k){
      const half2_t h2 = __builtin_bit_cast(half2_t, __builtin_amdgcn_readlane(hv, k));
      a0 = __builtin_amdgcn_fdot2(__builtin_bit_cast(half2_t, wreg[0][k]), h2, a0, false);
      a1 = __builtin_amdgcn_fdot2(__builtin_bit_cast(half2_t, wreg[1][k]), h2, a1, false);
      a2 = __builtin_amdgcn_fdot2(__builtin_bit_cast(half2_t, wreg[2][k]), h2, a2, false);
      a3 = __builtin_amdgcn_fdot2(__builtin_bit_cast(half2_t, wreg[3][k]), h2, a3, false);
    }
    // LDS-weight section
    #pragma unroll
    for (int k=0; k<KLDS2; ++k){
      const uint4 w = wlds[k*512 + tid];
      const half2_t h2 = __builtin_bit_cast(half2_t, __builtin_amdgcn_readlane(hv, KREG2 + k));
      a0 = __builtin_amdgcn_fdot2(__builtin_bit_cast(half2_t, w.x), h2, a0, false);
      a1 = __builtin_amdgcn_fdot2(__builtin_bit_cast(half2_t, w.y), h2, a1, false);
      a2 = __builtin_amdgcn_fdot2(__builtin_bit_cast(half2_t, w.z), h2, a2, false);
      a3 = __builtin_amdgcn_fdot2(__builtin_bit_cast(half2_t, w.w), h2, a3, false);
    }

    if (kh){ float4 r; r.x=a0; r.y=a1; r.z=a2; r.w=a3; red[j] = r; }
    __syncthreads();
    if (!kh){
      const float4 r = red[j];
      const half2_t xlo = __builtin_bit_cast(half2_t, xv.x);
      const half2_t xhi = __builtin_bit_cast(half2_t, xv.y);
      a0 += r.x + (float)xlo.x;
      a1 += r.y + (float)xlo.y;
      a2 += r.z + (float)xhi.x;
      a3 += r.w + (float)xhi.y;
      const float gi = sigf(a0);
      const float gf = sigf(a1);
      const float gg = tanh_f(a2);
      const float go = sigf(a3);
      c = gf*c + gi*gg;
      const float h = go * tanh_f(c);

      const half_t hh16 = (half_t)h;
      ((unsigned short*)(hbuf + (t&1)*128))[j] = __builtin_bit_cast(unsigned short, hh16);
      if (wr32) h32[(base + t)*H_N + j] = h;
      else      h16[(base + t)*H_N + j] = hh16;
      if (t == S_N-1){ hT[b*H_N + j] = h; cT[b*H_N + j] = c; }
    }
    xv = xnext;
    __syncthreads();   // h-write visible; WAR on red + h buffers
  }
}

extern "C" void kernel_launch(void* const* d_in, const int* in_sizes, int n_in,
                              void* d_out, int out_size, void* d_ws, size_t ws_size,
                              hipStream_t stream)
{
  const float* x   = (const float*)d_in[0];
  const float* Wih = (const float*)d_in[1];
  const float* bih = (const float*)d_in[2];
  const float* Whh = (const float*)d_in[3];
  const float* bhh = (const float*)d_in[4];
  float* out = (float*)d_out;

  char* ws = (char*)d_ws;
  half_t* A0   = (half_t*)(ws + WS_A0);    // layer-0 fp16 input; reused as h0 sequence
  half_t* XP   = (half_t*)(ws + WS_XP);
  half_t* Wi16 = (half_t*)(ws + WS_WI);
  half_t* Wh16 = (half_t*)(ws + WS_WH);
  float*  bsum = (float*)(ws + WS_BSUM);

  cvt_f32_f16<<<dim3(M_N*H_N/256), dim3(256), 0, stream>>>(x, A0, M_N*H_N);
  cvt_f32_f16<<<dim3(L_N*G_N*H_N/256), dim3(256), 0, stream>>>(Wih, Wi16, L_N*G_N*H_N);
  cvt_f32_f16<<<dim3(L_N*G_N*H_N/256), dim3(256), 0, stream>>>(Whh, Wh16, L_N*G_N*H_N);
  make_bsum<<<dim3(L_N*G_N/256), dim3(256), 0, stream>>>(bih, bhh, bsum, L_N*G_N);

  float* hT = out + (size_t)M_N*H_N;       // hs [2][32][256]
  float* cT = hT + (size_t)L_N*B_N*H_N;    // cs [2][32][256]

  // ---- layer 0
  gemm_xp<<<dim3(M_N/64, G_N/64), dim3(256), 0, stream>>>(A0, Wi16, bsum, XP);
  lstm_rec<<<dim3(B_N), dim3(512), SMEM_BYTES, stream>>>(
      (const uint32_t*)Wh16, XP, A0 /*h0 seq overwrites dead A0*/, nullptr,
      hT, cT, 0);

  // ---- layer 1
  gemm_xp<<<dim3(M_N/64, G_N/64), dim3(256), 0, stream>>>(A0, Wi16 + (size_t)G_N*H_N, bsum + G_N, XP);
  lstm_rec<<<dim3(B_N), dim3(512), SMEM_BYTES, stream>>>(
      (const uint32_t*)(Wh16 + (size_t)G_N*H_N), XP, nullptr, out,
      hT + B_N*H_N, cT + B_N*H_N, 1);
}

// Round 4
// 6987.091 us; speedup vs baseline: 1.1305x; 1.1305x over previous
//
#include <hip/hip_runtime.h>
#include <cstdint>
#include <cstddef>

typedef _Float16 half_t;
typedef _Float16 half2_t __attribute__((ext_vector_type(2)));
typedef _Float16 half8_t __attribute__((ext_vector_type(8)));
typedef float   float4_t __attribute__((ext_vector_type(4)));

#define L_N 2
#define B_N 32
#define S_N 2048
#define H_N 256
#define G_N 1024            // 4H
#define M_N (B_N*S_N)       // 65536

// Recurrent kernel: 512 threads = 2 K-halves x 256 cells.
// Per thread: 4 gate rows x 64 pairs; KREG2 pairs in VGPRs, KLDS2 in LDS.
#define KREG2 48
#define KLDS2 16
#define SMEM_WT   (KLDS2*512*16)            // 131072 B weight tiles
#define SMEM_HB   (2*128*4)                 // double-buffered h pairs
#define SMEM_RED  (256*16)                  // float4 partial-sum reduce
#define SMEM_BYTES (SMEM_WT + SMEM_HB + SMEM_RED)

// ws layout (bytes)
#define WS_A0   0ull                 // fp16 [M][H]: layer-0 A; later reused as h0 sequence
#define WS_XP   33554432ull          // fp16 [M][G]: input projection, packed [m][cell][4]
#define WS_WI   167772160ull         // fp16 [L][G][H]
#define WS_WH   168820736ull         // fp16 [L][G][H]
#define WS_BSUM 169869312ull         // f32 [L][G]  (b_ih + b_hh)

__global__ void cvt_f32_f16(const float* __restrict__ in, half_t* __restrict__ out, int n){
  int i = blockIdx.x*256 + threadIdx.x;
  if (i < n) out[i] = (half_t)in[i];
}

__global__ void make_bsum(const float* __restrict__ bi, const float* __restrict__ bh,
                          float* __restrict__ bs, int n){
  int i = blockIdx.x*256 + threadIdx.x;
  if (i < n) bs[i] = bi[i] + bh[i];
}

// XP[m, cell, gate] = sum_k A[m,k] * W[gate*256+cell, k] + bsum[...]
// Output packed so one cell's 4 gate pre-activations are adjacent.
__global__ __launch_bounds__(256) void gemm_xp(
    const half_t* __restrict__ A, const half_t* __restrict__ W,
    const float* __restrict__ bsum, half_t* __restrict__ XP)
{
  const int wave = threadIdx.x >> 6;
  const int lane = threadIdx.x & 63;
  const int l15 = lane & 15, quad = lane >> 4;
  const int m0 = blockIdx.x*64 + wave*16;
  const int n0 = blockIdx.y*64;
  float4_t acc[4] = {{0,0,0,0},{0,0,0,0},{0,0,0,0},{0,0,0,0}};
  const half_t* arow = A + (size_t)(m0 + l15)*H_N + quad*8;
  const half_t* brow[4];
  #pragma unroll
  for (int nt=0; nt<4; ++nt)
    brow[nt] = W + (size_t)(n0 + nt*16 + l15)*H_N + quad*8;
  #pragma unroll
  for (int k0=0; k0<H_N; k0+=32){
    half8_t af = *(const half8_t*)(arow + k0);
    #pragma unroll
    for (int nt=0; nt<4; ++nt){
      half8_t bf = *(const half8_t*)(brow[nt] + k0);
      acc[nt] = __builtin_amdgcn_mfma_f32_16x16x32_f16(af, bf, acc[nt], 0, 0, 0);
    }
  }
  #pragma unroll
  for (int nt=0; nt<4; ++nt){
    const int col = n0 + nt*16 + l15;          // gate row g in [0,1024)
    const int cell = col & 255, gate = col >> 8;
    const float bs = bsum[col];
    #pragma unroll
    for (int r=0; r<4; ++r){
      XP[(size_t)(m0 + quad*4 + r)*G_N + cell*4 + gate] = (half_t)(acc[nt][r] + bs);
    }
  }
}

__device__ __forceinline__ float sigf(float x){ return 1.f/(1.f + __expf(-x)); }
__device__ __forceinline__ float tanh_f(float x){ return 1.f - 2.f/(__expf(2.f*x) + 1.f); }

// Persistent per-batch-chain LSTM recurrence. 1 block = 1 chain = 1 CU.
// 512 threads: tid = (kh<<8)|j. Thread owns gates {j,j+256,j+512,j+768} over
// K-pairs [kh*64, kh*64+64). h broadcast via LDS b128 (same-address = free),
// software-pipelined 2 groups ahead so the ~120cyc LDS latency hides under
// the fdot2 chain. Weights: 48 pairs/gate in regs, 16 pairs/gate in LDS.
__global__ __launch_bounds__(512,2) void lstm_rec(
    const uint32_t* __restrict__ Wp,   // fp16-pair view of Wh [1024][128]
    const half_t*  __restrict__ xp,    // [M][1024], packed [m][cell][4], biases folded
    half_t* __restrict__ h16,          // layer-0 h sequence out (fp16)
    float*  __restrict__ h32,          // layer-1 h sequence out (fp32, = d_out x)
    float*  __restrict__ hT, float* __restrict__ cT, int wr32)
{
  extern __shared__ unsigned char smem[];
  uint4*    wlds = (uint4*)smem;                     // [KLDS2][512]
  uint32_t* hbuf = (uint32_t*)(smem + SMEM_WT);      // [2][128] h pairs
  float4*   red  = (float4*)(smem + SMEM_WT + SMEM_HB); // [256]
  const int tid = threadIdx.x;
  const int j  = tid & 255;
  const int kh = tid >> 8;
  const int b  = blockIdx.x;

  // --- VGPR-resident weights: pairs kh*64 + [0, KREG2) of each of 4 gate rows
  uint32_t wreg[4][KREG2];
  #pragma unroll
  for (int q=0; q<4; ++q){
    const uint32_t* wp = Wp + (size_t)(q*256 + j)*128 + kh*64;
    #pragma unroll
    for (int k=0; k<KREG2; ++k) wreg[q][k] = wp[k];
  }
  // --- LDS-resident weights: pairs kh*64 + KREG2 + [0, KLDS2), 4 gates packed per uint4
  {
    const uint32_t* w0 = Wp + (size_t)(  0 + j)*128 + kh*64 + KREG2;
    const uint32_t* w1 = Wp + (size_t)(256 + j)*128 + kh*64 + KREG2;
    const uint32_t* w2 = Wp + (size_t)(512 + j)*128 + kh*64 + KREG2;
    const uint32_t* w3 = Wp + (size_t)(768 + j)*128 + kh*64 + KREG2;
    #pragma unroll
    for (int k=0; k<KLDS2; ++k){
      uint4 v; v.x = w0[k]; v.y = w1[k]; v.z = w2[k]; v.w = w3[k];
      wlds[k*512 + tid] = v;
    }
  }
  if (tid < 128) hbuf[128 + tid] = 0u;   // initial h (read buffer of t=0) = 0
  float c = 0.f;
  __syncthreads();

  const size_t base = (size_t)b * S_N;
  // software-pipelined xp load (kh=0 threads only; wave-uniform branch)
  uint2 xv = {0,0};
  if (!kh) xv = *(const uint2*)(xp + base*G_N + j*4);

  for (int t=0; t<S_N; ++t){
    const uint4* hr4 = (const uint4*)(hbuf + ((t+1)&1)*128 + kh*64);

    // next-step xp prefetch issued first: max slack before the barrier drain
    uint2 xnext = {0,0};
    if (!kh && t+1 < S_N) xnext = *(const uint2*)(xp + (base+t+1)*G_N + j*4);

    // h pipeline: distance-2 prefetch across all 16 groups
    uint4 hp0 = hr4[0];
    uint4 hp1 = hr4[1];
    float a0=0.f, a1=0.f, a2=0.f, a3=0.f;

    #pragma unroll
    for (int g=0; g<16; ++g){
      const uint4 cur = hp0;
      hp0 = hp1;
      if (g+2 < 16) hp1 = hr4[g+2];
      if (g < KREG2/4){
        // VGPR-weight groups
        #pragma unroll
        for (int p=0; p<4; ++p){
          const int k = g*4 + p;
          const half2_t h2 = __builtin_bit_cast(half2_t, (&cur.x)[p]);
          a0 = __builtin_amdgcn_fdot2(__builtin_bit_cast(half2_t, wreg[0][k]), h2, a0, false);
          a1 = __builtin_amdgcn_fdot2(__builtin_bit_cast(half2_t, wreg[1][k]), h2, a1, false);
          a2 = __builtin_amdgcn_fdot2(__builtin_bit_cast(half2_t, wreg[2][k]), h2, a2, false);
          a3 = __builtin_amdgcn_fdot2(__builtin_bit_cast(half2_t, wreg[3][k]), h2, a3, false);
        }
      } else {
        // LDS-weight groups
        #pragma unroll
        for (int p=0; p<4; ++p){
          const uint4 w = wlds[((g - KREG2/4)*4 + p)*512 + tid];
          const half2_t h2 = __builtin_bit_cast(half2_t, (&cur.x)[p]);
          a0 = __builtin_amdgcn_fdot2(__builtin_bit_cast(half2_t, w.x), h2, a0, false);
          a1 = __builtin_amdgcn_fdot2(__builtin_bit_cast(half2_t, w.y), h2, a1, false);
          a2 = __builtin_amdgcn_fdot2(__builtin_bit_cast(half2_t, w.z), h2, a2, false);
          a3 = __builtin_amdgcn_fdot2(__builtin_bit_cast(half2_t, w.w), h2, a3, false);
        }
      }
    }

    if (kh){ float4 r; r.x=a0; r.y=a1; r.z=a2; r.w=a3; red[j] = r; }
    __syncthreads();
    if (!kh){
      const float4 r = red[j];
      const half2_t xlo = __builtin_bit_cast(half2_t, xv.x);
      const half2_t xhi = __builtin_bit_cast(half2_t, xv.y);
      a0 += r.x + (float)xlo.x;
      a1 += r.y + (float)xlo.y;
      a2 += r.z + (float)xhi.x;
      a3 += r.w + (float)xhi.y;
      const float gi = sigf(a0);
      const float gf = sigf(a1);
      const float gg = tanh_f(a2);
      const float go = sigf(a3);
      c = gf*c + gi*gg;
      const float h = go * tanh_f(c);

      const half_t hh16 = (half_t)h;
      ((unsigned short*)(hbuf + (t&1)*128))[j] = __builtin_bit_cast(unsigned short, hh16);
      if (wr32) h32[(base + t)*H_N + j] = h;
      else      h16[(base + t)*H_N + j] = hh16;
      if (t == S_N-1){ hT[b*H_N + j] = h; cT[b*H_N + j] = c; }
    }
    xv = xnext;
    __syncthreads();   // h-write visible; WAR on red + h buffers
  }
}

extern "C" void kernel_launch(void* const* d_in, const int* in_sizes, int n_in,
                              void* d_out, int out_size, void* d_ws, size_t ws_size,
                              hipStream_t stream)
{
  const float* x   = (const float*)d_in[0];
  const float* Wih = (const float*)d_in[1];
  const float* bih = (const float*)d_in[2];
  const float* Whh = (const float*)d_in[3];
  const float* bhh = (const float*)d_in[4];
  float* out = (float*)d_out;

  char* ws = (char*)d_ws;
  half_t* A0   = (half_t*)(ws + WS_A0);    // layer-0 fp16 input; reused as h0 sequence
  half_t* XP   = (half_t*)(ws + WS_XP);
  half_t* Wi16 = (half_t*)(ws + WS_WI);
  half_t* Wh16 = (half_t*)(ws + WS_WH);
  float*  bsum = (float*)(ws + WS_BSUM);

  cvt_f32_f16<<<dim3(M_N*H_N/256), dim3(256), 0, stream>>>(x, A0, M_N*H_N);
  cvt_f32_f16<<<dim3(L_N*G_N*H_N/256), dim3(256), 0, stream>>>(Wih, Wi16, L_N*G_N*H_N);
  cvt_f32_f16<<<dim3(L_N*G_N*H_N/256), dim3(256), 0, stream>>>(Whh, Wh16, L_N*G_N*H_N);
  make_bsum<<<dim3(L_N*G_N/256), dim3(256), 0, stream>>>(bih, bhh, bsum, L_N*G_N);

  float* hT = out + (size_t)M_N*H_N;       // hs [2][32][256]
  float* cT = hT + (size_t)L_N*B_N*H_N;    // cs [2][32][256]

  // ---- layer 0
  gemm_xp<<<dim3(M_N/64, G_N/64), dim3(256), 0, stream>>>(A0, Wi16, bsum, XP);
  lstm_rec<<<dim3(B_N), dim3(512), SMEM_BYTES, stream>>>(
      (const uint32_t*)Wh16, XP, A0 /*h0 seq overwrites dead A0*/, nullptr,
      hT, cT, 0);

  // ---- layer 1
  gemm_xp<<<dim3(M_N/64, G_N/64), dim3(256), 0, stream>>>(A0, Wi16 + (size_t)G_N*H_N, bsum + G_N, XP);
  lstm_rec<<<dim3(B_N), dim3(512), SMEM_BYTES, stream>>>(
      (const uint32_t*)(Wh16 + (size_t)G_N*H_N), XP, nullptr, out,
      hT + B_N*H_N, cT + B_N*H_N, 1);
}

// Round 5
// 6921.174 us; speedup vs baseline: 1.1412x; 1.0095x over previous
//
#include <hip/hip_runtime.h>
#include <cstdint>
#include <cstddef>

typedef _Float16 half_t;
typedef _Float16 half2_t __attribute__((ext_vector_type(2)));
typedef _Float16 half8_t __attribute__((ext_vector_type(8)));
typedef float   float4_t __attribute__((ext_vector_type(4)));

#define L_N 2
#define B_N 32
#define S_N 2048
#define H_N 256
#define G_N 1024            // 4H
#define M_N (B_N*S_N)       // 65536

// Recurrent kernel: 512 threads = 2 K-halves x 256 cells.
// Per thread: 4 gate rows x 64 pairs; KREG2 pairs in VGPRs, KLDS2 in LDS.
#define KREG2 48
#define KLDS2 16
#define SMEM_WT   (KLDS2*512*16)            // 131072 B weight tiles
#define SMEM_HB   (2*128*4)                 // double-buffered h pairs
#define SMEM_RED  (256*16)                  // float4 partial-sum reduce
#define SMEM_BYTES (SMEM_WT + SMEM_HB + SMEM_RED)

// ws layout (bytes)
#define WS_A0   0ull                 // fp16 [M][H]: layer-0 A; later reused as h0 sequence
#define WS_XP   33554432ull          // fp16 [M][G]: input projection, packed [m][cell][4]
#define WS_WI   167772160ull         // fp16 [L][G][H]
#define WS_WH   168820736ull         // fp16 [L][G][H]
#define WS_BSUM 169869312ull         // f32 [L][G]  (b_ih + b_hh)

__global__ void cvt_f32_f16(const float* __restrict__ in, half_t* __restrict__ out, int n){
  int i = blockIdx.x*256 + threadIdx.x;
  if (i < n) out[i] = (half_t)in[i];
}

__global__ void make_bsum(const float* __restrict__ bi, const float* __restrict__ bh,
                          float* __restrict__ bs, int n){
  int i = blockIdx.x*256 + threadIdx.x;
  if (i < n) bs[i] = bi[i] + bh[i];
}

// XP[m, cell, gate] = sum_k A[m,k] * W[gate*256+cell, k] + bsum[...]
// Output packed so one cell's 4 gate pre-activations are adjacent.
__global__ __launch_bounds__(256) void gemm_xp(
    const half_t* __restrict__ A, const half_t* __restrict__ W,
    const float* __restrict__ bsum, half_t* __restrict__ XP)
{
  const int wave = threadIdx.x >> 6;
  const int lane = threadIdx.x & 63;
  const int l15 = lane & 15, quad = lane >> 4;
  const int m0 = blockIdx.x*64 + wave*16;
  const int n0 = blockIdx.y*64;
  float4_t acc[4] = {{0,0,0,0},{0,0,0,0},{0,0,0,0},{0,0,0,0}};
  const half_t* arow = A + (size_t)(m0 + l15)*H_N + quad*8;
  const half_t* brow[4];
  #pragma unroll
  for (int nt=0; nt<4; ++nt)
    brow[nt] = W + (size_t)(n0 + nt*16 + l15)*H_N + quad*8;
  #pragma unroll
  for (int k0=0; k0<H_N; k0+=32){
    half8_t af = *(const half8_t*)(arow + k0);
    #pragma unroll
    for (int nt=0; nt<4; ++nt){
      half8_t bf = *(const half8_t*)(brow[nt] + k0);
      acc[nt] = __builtin_amdgcn_mfma_f32_16x16x32_f16(af, bf, acc[nt], 0, 0, 0);
    }
  }
  #pragma unroll
  for (int nt=0; nt<4; ++nt){
    const int col = n0 + nt*16 + l15;          // gate row g in [0,1024)
    const int cell = col & 255, gate = col >> 8;
    const float bs = bsum[col];
    #pragma unroll
    for (int r=0; r<4; ++r){
      XP[(size_t)(m0 + quad*4 + r)*G_N + cell*4 + gate] = (half_t)(acc[nt][r] + bs);
    }
  }
}

__device__ __forceinline__ float sigf(float x){ return 1.f/(1.f + __expf(-x)); }
__device__ __forceinline__ float tanh_f(float x){ return 1.f - 2.f/(__expf(2.f*x) + 1.f); }

// Persistent per-batch-chain LSTM recurrence. 1 block = 1 chain = 1 CU.
// 512 threads: tid = (kh<<8)|j. Thread owns gates {j,j+256,j+512,j+768} over
// K-pairs [kh*64, kh*64+64). waves_per_eu(2,2): exactly 2 waves/SIMD ->
// 256-reg unified budget per thread, so the 192 weight pairs should land in
// ARCHITECTURAL VGPRs (no accvgpr round-trips). Discriminates VALU-inflation
// theory vs LDS-bus theory.
__global__ __launch_bounds__(512,2) __attribute__((amdgpu_waves_per_eu(2,2)))
void lstm_rec(
    const uint32_t* __restrict__ Wp,   // fp16-pair view of Wh [1024][128]
    const half_t*  __restrict__ xp,    // [M][1024], packed [m][cell][4], biases folded
    half_t* __restrict__ h16,          // layer-0 h sequence out (fp16)
    float*  __restrict__ h32,          // layer-1 h sequence out (fp32, = d_out x)
    float*  __restrict__ hT, float* __restrict__ cT, int wr32)
{
  extern __shared__ unsigned char smem[];
  uint4*    wlds = (uint4*)smem;                     // [KLDS2][512]
  uint32_t* hbuf = (uint32_t*)(smem + SMEM_WT);      // [2][128] h pairs
  float4*   red  = (float4*)(smem + SMEM_WT + SMEM_HB); // [256]
  const int tid = threadIdx.x;
  const int j  = tid & 255;
  const int kh = tid >> 8;
  const int b  = blockIdx.x;

  // --- VGPR-resident weights: pairs kh*64 + [0, KREG2) of each of 4 gate rows
  uint32_t wreg[4][KREG2];
  #pragma unroll
  for (int q=0; q<4; ++q){
    const uint32_t* wp = Wp + (size_t)(q*256 + j)*128 + kh*64;
    #pragma unroll
    for (int k=0; k<KREG2; ++k) wreg[q][k] = wp[k];
  }
  // --- LDS-resident weights: pairs kh*64 + KREG2 + [0, KLDS2), 4 gates packed per uint4
  {
    const uint32_t* w0 = Wp + (size_t)(  0 + j)*128 + kh*64 + KREG2;
    const uint32_t* w1 = Wp + (size_t)(256 + j)*128 + kh*64 + KREG2;
    const uint32_t* w2 = Wp + (size_t)(512 + j)*128 + kh*64 + KREG2;
    const uint32_t* w3 = Wp + (size_t)(768 + j)*128 + kh*64 + KREG2;
    #pragma unroll
    for (int k=0; k<KLDS2; ++k){
      uint4 v; v.x = w0[k]; v.y = w1[k]; v.z = w2[k]; v.w = w3[k];
      wlds[k*512 + tid] = v;
    }
  }
  if (tid < 128) hbuf[128 + tid] = 0u;   // initial h (read buffer of t=0) = 0
  float c = 0.f;
  __syncthreads();

  const size_t base = (size_t)b * S_N;
  // software-pipelined xp load (kh=0 threads only; wave-uniform branch)
  uint2 xv = {0,0};
  if (!kh) xv = *(const uint2*)(xp + base*G_N + j*4);

  for (int t=0; t<S_N; ++t){
    const uint4* hr4 = (const uint4*)(hbuf + ((t+1)&1)*128 + kh*64);

    // next-step xp prefetch issued first: max slack before the barrier drain
    uint2 xnext = {0,0};
    if (!kh && t+1 < S_N) xnext = *(const uint2*)(xp + (base+t+1)*G_N + j*4);

    float a0=0.f, a1=0.f, a2=0.f, a3=0.f;

    // VGPR-weight section: grouped b128 h broadcasts, compiler-scheduled
    #pragma unroll
    for (int k8=0; k8<KREG2/4; ++k8){
      const uint4 hh = hr4[k8];
      #pragma unroll
      for (int p=0; p<4; ++p){
        const int k = k8*4 + p;
        const half2_t h2 = __builtin_bit_cast(half2_t, (&hh.x)[p]);
        a0 = __builtin_amdgcn_fdot2(__builtin_bit_cast(half2_t, wreg[0][k]), h2, a0, false);
        a1 = __builtin_amdgcn_fdot2(__builtin_bit_cast(half2_t, wreg[1][k]), h2, a1, false);
        a2 = __builtin_amdgcn_fdot2(__builtin_bit_cast(half2_t, wreg[2][k]), h2, a2, false);
        a3 = __builtin_amdgcn_fdot2(__builtin_bit_cast(half2_t, wreg[3][k]), h2, a3, false);
      }
    }
    // LDS-weight section
    #pragma unroll
    for (int k8=0; k8<KLDS2/4; ++k8){
      const uint4 hh = hr4[KREG2/4 + k8];
      #pragma unroll
      for (int p=0; p<4; ++p){
        const uint4 w = wlds[(k8*4+p)*512 + tid];
        const half2_t h2 = __builtin_bit_cast(half2_t, (&hh.x)[p]);
        a0 = __builtin_amdgcn_fdot2(__builtin_bit_cast(half2_t, w.x), h2, a0, false);
        a1 = __builtin_amdgcn_fdot2(__builtin_bit_cast(half2_t, w.y), h2, a1, false);
        a2 = __builtin_amdgcn_fdot2(__builtin_bit_cast(half2_t, w.z), h2, a2, false);
        a3 = __builtin_amdgcn_fdot2(__builtin_bit_cast(half2_t, w.w), h2, a3, false);
      }
    }

    if (kh){ float4 r; r.x=a0; r.y=a1; r.z=a2; r.w=a3; red[j] = r; }
    __syncthreads();
    if (!kh){
      const float4 r = red[j];
      const half2_t xlo = __builtin_bit_cast(half2_t, xv.x);
      const half2_t xhi = __builtin_bit_cast(half2_t, xv.y);
      a0 += r.x + (float)xlo.x;
      a1 += r.y + (float)xlo.y;
      a2 += r.z + (float)xhi.x;
      a3 += r.w + (float)xhi.y;
      const float gi = sigf(a0);
      const float gf = sigf(a1);
      const float gg = tanh_f(a2);
      const float go = sigf(a3);
      c = gf*c + gi*gg;
      const float h = go * tanh_f(c);

      const half_t hh16 = (half_t)h;
      ((unsigned short*)(hbuf + (t&1)*128))[j] = __builtin_bit_cast(unsigned short, hh16);
      if (wr32) h32[(base + t)*H_N + j] = h;
      else      h16[(base + t)*H_N + j] = hh16;
      if (t == S_N-1){ hT[b*H_N + j] = h; cT[b*H_N + j] = c; }
    }
    xv = xnext;
    __syncthreads();   // h-write visible; WAR on red + h buffers
  }
}

extern "C" void kernel_launch(void* const* d_in, const int* in_sizes, int n_in,
                              void* d_out, int out_size, void* d_ws, size_t ws_size,
                              hipStream_t stream)
{
  const float* x   = (const float*)d_in[0];
  const float* Wih = (const float*)d_in[1];
  const float* bih = (const float*)d_in[2];
  const float* Whh = (const float*)d_in[3];
  const float* bhh = (const float*)d_in[4];
  float* out = (float*)d_out;

  char* ws = (char*)d_ws;
  half_t* A0   = (half_t*)(ws + WS_A0);    // layer-0 fp16 input; reused as h0 sequence
  half_t* XP   = (half_t*)(ws + WS_XP);
  half_t* Wi16 = (half_t*)(ws + WS_WI);
  half_t* Wh16 = (half_t*)(ws + WS_WH);
  float*  bsum = (float*)(ws + WS_BSUM);

  cvt_f32_f16<<<dim3(M_N*H_N/256), dim3(256), 0, stream>>>(x, A0, M_N*H_N);
  cvt_f32_f16<<<dim3(L_N*G_N*H_N/256), dim3(256), 0, stream>>>(Wih, Wi16, L_N*G_N*H_N);
  cvt_f32_f16<<<dim3(L_N*G_N*H_N/256), dim3(256), 0, stream>>>(Whh, Wh16, L_N*G_N*H_N);
  make_bsum<<<dim3(L_N*G_N/256), dim3(256), 0, stream>>>(bih, bhh, bsum, L_N*G_N);

  float* hT = out + (size_t)M_N*H_N;       // hs [2][32][256]
  float* cT = hT + (size_t)L_N*B_N*H_N;    // cs [2][32][256]

  // ---- layer 0
  gemm_xp<<<dim3(M_N/64, G_N/64), dim3(256), 0, stream>>>(A0, Wi16, bsum, XP);
  lstm_rec<<<dim3(B_N), dim3(512), SMEM_BYTES, stream>>>(
      (const uint32_t*)Wh16, XP, A0 /*h0 seq overwrites dead A0*/, nullptr,
      hT, cT, 0);

  // ---- layer 1
  gemm_xp<<<dim3(M_N/64, G_N/64), dim3(256), 0, stream>>>(A0, Wi16 + (size_t)G_N*H_N, bsum + G_N, XP);
  lstm_rec<<<dim3(B_N), dim3(512), SMEM_BYTES, stream>>>(
      (const uint32_t*)(Wh16 + (size_t)G_N*H_N), XP, nullptr, out,
      hT + B_N*H_N, cT + B_N*H_N, 1);
}